// Round 2
// baseline (72.905 us; speedup 1.0000x reference)
//
#include <hip/hip_runtime.h>
#include <math.h>

#define BB 256
#define NN 50
#define DD 128
#define HS 132          // h row stride (floats): +4 pad -> 16B-aligned rows for float4
#define AS 52           // alpha row stride
#define SPLIT 4         // GAT blocks per batch
#define ROWS 13         // ceil(50/4)
#define MAXA 2000
#define NEGV -9e15f

__global__ __launch_bounds__(256) void sg_fused_kernel(
    const int* __restrict__ inputs,      // [B,N]
    const int* __restrict__ adj,         // [B,N,N]
    const float* __restrict__ A_attr,    // [B,MAXA]
    const float* __restrict__ embedding, // [N_NODE,D]
    const float* __restrict__ attr_emb,  // [MAXA,D]
    const float* __restrict__ a0,
    const float* __restrict__ a1,
    const float* __restrict__ a2,
    const float* __restrict__ a3,
    float* __restrict__ out,             // [B,N,D]
    float* __restrict__ attr_out)        // [B,D]
{
    // one buffer, aliased by both halves of the grid (keeps LDS footprint = max, not sum)
    __shared__ __align__(16) float smem[NN * HS + 4 * HS + ROWS * AS];
    const int blk = blockIdx.x;
    const int tid = threadIdx.x;

    if (blk < BB * SPLIT) {
        // ---------------- GAT: 4 blocks per batch, 13 rows each ----------------
        float* h     = smem;                 // [NN][HS]
        float* av    = smem + NN * HS;       // [4][HS]
        float* alpha = av + 4 * HS;          // [ROWS][AS]
        const int b    = blk >> 2;
        const int part = blk & 3;
        const int r0   = part * ROWS;
        const int r1   = (r0 + ROWS < NN) ? r0 + ROWS : NN;

        if (tid < DD) {
            av[0 * HS + tid] = a0[tid];
            av[1 * HS + tid] = a1[tid];
            av[2 * HS + tid] = a2[tid];
            av[3 * HS + tid] = a3[tid];
        }
        // stage h = embedding[inputs[b]] as float4: 50*32 = 1600 items
        for (int idx = tid; idx < NN * DD / 4; idx += 256) {
            const int i  = idx >> 5;
            const int d4 = idx & 31;
            const int node = inputs[b * NN + i];
            const float4 v = *(const float4*)(embedding + (size_t)node * DD + d4 * 4);
            *(float4*)(h + i * HS + d4 * 4) = v;
        }
        __syncthreads();

        // scores + in-register softmax: wave per row i, lane per column j
        const int wave = tid >> 6;
        const int lane = tid & 63;
        for (int i = r0 + wave; i < r1; i += 4) {
            float e = -INFINITY;  // pad lanes contribute exp()=0
            if (lane < NN) {
                const int a = adj[((size_t)b * NN + i) * NN + lane];
                if (a == 0) {
                    e = NEGV;
                } else {
                    const float4* hi4 = (const float4*)(h + i * HS);
                    const float4* hj4 = (const float4*)(h + lane * HS);
                    const float4* as4 = (const float4*)(av + (a - 1) * HS);
                    float ax = 0.f, ay = 0.f, az = 0.f, aw = 0.f;  // 4 indep chains
                    #pragma unroll 8
                    for (int d4 = 0; d4 < DD / 4; ++d4) {
                        const float4 x = hi4[d4], y = hj4[d4], aa = as4[d4];
                        float px = x.x * y.x, py = x.y * y.y;
                        float pz = x.z * y.z, pw = x.w * y.w;
                        px = fmaxf(px, 0.2f * px); py = fmaxf(py, 0.2f * py);
                        pz = fmaxf(pz, 0.2f * pz); pw = fmaxf(pw, 0.2f * pw);
                        ax = fmaf(px, aa.x, ax); ay = fmaf(py, aa.y, ay);
                        az = fmaf(pz, aa.z, az); aw = fmaf(pw, aa.w, aw);
                    }
                    e = (ax + ay) + (az + aw);
                }
            }
            float m = e;
            for (int off = 32; off; off >>= 1)
                m = fmaxf(m, __shfl_xor(m, off));
            const float ex = (lane < NN) ? __expf(e - m) : 0.f;
            float s = ex;
            for (int off = 32; off; off >>= 1)
                s += __shfl_xor(s, off);
            if (lane < NN) alpha[(i - r0) * AS + lane] = ex / s;
        }
        __syncthreads();

        // output rows r0..r1-1 = alpha @ h, float4 per work item
        const int nr = r1 - r0;
        for (int idx = tid; idx < nr * (DD / 4); idx += 256) {
            const int ri = idx >> 5;
            const int d4 = idx & 31;
            const float* al = alpha + ri * AS;
            float ax = 0.f, ay = 0.f, az = 0.f, aw = 0.f;
            #pragma unroll 10
            for (int j = 0; j < NN; ++j) {
                const float4 hv = *(const float4*)(h + j * HS + d4 * 4);
                const float w = al[j];
                ax = fmaf(w, hv.x, ax); ay = fmaf(w, hv.y, ay);
                az = fmaf(w, hv.z, az); aw = fmaf(w, hv.w, aw);
            }
            float4 o; o.x = ax; o.y = ay; o.z = az; o.w = aw;
            *(float4*)(out + ((size_t)b * NN + r0 + ri) * DD + d4 * 4) = o;
        }
    } else {
        // ---------- attr_sess = A_attr @ attr_emb : 2 rows/block, 2-way k-split ----------
        float* red = smem;                  // [2][2][DD] = 512 floats
        const int b0 = (blk - BB * SPLIT) * 2;
        const int d  = tid & 127;
        const int kh = tid >> 7;
        const float* Ar0 = A_attr + (size_t)(b0 + 0) * MAXA;
        const float* Ar1 = A_attr + (size_t)(b0 + 1) * MAXA;
        float c0a = 0.f, c0b = 0.f, c1a = 0.f, c1b = 0.f;  // 4 indep chains
        const int k0 = kh * (MAXA / 2);
        for (int k = k0; k < k0 + MAXA / 2; k += 2) {
            const float e0 = attr_emb[(size_t)k * DD + d];
            const float e1 = attr_emb[(size_t)(k + 1) * DD + d];
            const float w00 = Ar0[k], w01 = Ar0[k + 1];
            const float w10 = Ar1[k], w11 = Ar1[k + 1];
            c0a = fmaf(w00, e0, c0a); c0b = fmaf(w01, e1, c0b);
            c1a = fmaf(w10, e0, c1a); c1b = fmaf(w11, e1, c1b);
        }
        red[(kh * 2 + 0) * DD + d] = c0a + c0b;
        red[(kh * 2 + 1) * DD + d] = c1a + c1b;
        __syncthreads();
        if (tid < 2 * DD) {
            const int r  = tid >> 7;
            const int dd = tid & 127;
            attr_out[(size_t)(b0 + r) * DD + dd] =
                red[(0 * 2 + r) * DD + dd] + red[(1 * 2 + r) * DD + dd];
        }
    }
}

extern "C" void kernel_launch(void* const* d_in, const int* in_sizes, int n_in,
                              void* d_out, int out_size, void* d_ws, size_t ws_size,
                              hipStream_t stream) {
    const int*   inputs    = (const int*)  d_in[0];
    const int*   adj       = (const int*)  d_in[1];
    // d_in[2] = mask_item (unused by the reference)
    const float* A_attr    = (const float*)d_in[3];
    const float* embedding = (const float*)d_in[4];
    const float* attr_emb  = (const float*)d_in[5];
    const float* a0        = (const float*)d_in[6];
    const float* a1        = (const float*)d_in[7];
    const float* a2        = (const float*)d_in[8];
    const float* a3        = (const float*)d_in[9];

    float* out      = (float*)d_out;                 // [B,N,D] flat
    float* attr_out = out + (size_t)BB * NN * DD;    // [B,D] flat, concatenated

    const int grid = BB * SPLIT + BB / 2;  // 1024 GAT blocks + 128 attr blocks
    sg_fused_kernel<<<grid, 256, 0, stream>>>(inputs, adj, A_attr, embedding,
                                              attr_emb, a0, a1, a2, a3,
                                              out, attr_out);
}

// Round 3
// 61.429 us; speedup vs baseline: 1.1868x; 1.1868x over previous
//
#include <hip/hip_runtime.h>
#include <math.h>

#define BB 256
#define NN 50
#define DD 128
#define MAXA 2000
#define NEGV -9e15f

// LDS layout (ushort units). Row strides padded (+8 bf16 = +4 banks/row) so
// 16-lane fragment reads spread across banks (<=2-way aliasing = free).
#define H_S   136                    // H [64][H_S] bf16, rows 50..63 zero
#define HT_S  72                     // HT [128][HT_S] bf16, cols 50..63 zero
#define AL_S  72                     // alpha [64][AL_S] bf16
#define H_OFF  0
#define HT_OFF (64 * H_S)            // 8704
#define AL_OFF (HT_OFF + 128 * HT_S) // 17920
#define LDS_US (AL_OFF + 64 * AL_S)  // 22528 ushorts = 45056 B

typedef __attribute__((ext_vector_type(8))) short        s8b;    // 8 bf16 frag
typedef __attribute__((ext_vector_type(4))) float        f32x4;  // C/D frag
typedef __attribute__((ext_vector_type(4))) unsigned int u32x4;  // packed pairs

static __device__ __forceinline__ unsigned short f2bf(float x) {
    unsigned int u = __float_as_uint(x);
    u = u + 0x7fffu + ((u >> 16) & 1u);          // RNE
    return (unsigned short)(u >> 16);
}
static __device__ __forceinline__ float bf2f(unsigned int s) {
    return __uint_as_float(s << 16);
}
static __device__ __forceinline__ f32x4 mfma16(u32x4 a, u32x4 b, f32x4 c) {
    return __builtin_amdgcn_mfma_f32_16x16x32_bf16(
        __builtin_bit_cast(s8b, a), __builtin_bit_cast(s8b, b), c, 0, 0, 0);
}

__global__ __launch_bounds__(256) void sg_fused_kernel(
    const int* __restrict__ inputs,      // [B,N]
    const int* __restrict__ adj,         // [B,N,N]
    const float* __restrict__ A_attr,    // [B,MAXA]
    const float* __restrict__ embedding, // [N_NODE,D]
    const float* __restrict__ attr_emb,  // [MAXA,D]
    const float* __restrict__ a0,
    const float* __restrict__ a1,
    const float* __restrict__ a2,
    const float* __restrict__ a3,
    float* __restrict__ out,             // [B,N,D]
    float* __restrict__ attr_out)        // [B,D]
{
    __shared__ __align__(16) unsigned short sh[LDS_US];
    const int blk = blockIdx.x;
    const int tid = threadIdx.x;

    if (blk < BB) {
        // ================= GAT via MFMA: one block per batch =================
        const int b    = blk;
        const int it   = tid >> 6;        // wave id = i-tile (rows it*16..+15)
        const int lane = tid & 63;
        const int g    = lane >> 4;       // k-group
        const int c    = lane & 15;       // row/col within 16-tile
        const int goff = g * 8;           // k-slice offset (8 bf16)

        // ---- stage H (bf16, row-major) and HT (bf16, transposed); zero pads ----
        for (int idx = tid; idx < 64 * 32; idx += 256) {
            const int i  = idx >> 5;
            const int d4 = idx & 31;
            float4 v = make_float4(0.f, 0.f, 0.f, 0.f);
            if (i < NN) {
                const int node = inputs[b * NN + i];
                v = *(const float4*)(embedding + (size_t)node * DD + d4 * 4);
            }
            const unsigned short b0 = f2bf(v.x), b1 = f2bf(v.y);
            const unsigned short b2 = f2bf(v.z), b3 = f2bf(v.w);
            const unsigned int lo = (unsigned)b0 | ((unsigned)b1 << 16);
            const unsigned int hi = (unsigned)b2 | ((unsigned)b3 << 16);
            *(uint2*)(sh + H_OFF + i * H_S + d4 * 4) = make_uint2(lo, hi);
            sh[HT_OFF + (d4 * 4 + 0) * HT_S + i] = b0;
            sh[HT_OFF + (d4 * 4 + 1) * HT_S + i] = b1;
            sh[HT_OFF + (d4 * 4 + 2) * HT_S + i] = b2;
            sh[HT_OFF + (d4 * 4 + 3) * HT_S + i] = b3;
        }
        __syncthreads();

        // ---- scores: e_k = (H⊙0.6a_k)·H^T + (|H|⊙0.4a_k)·|H|^T via MFMA ----
        f32x4 accS[4][4];                 // [jt][k]
        #pragma unroll
        for (int jt = 0; jt < 4; ++jt)
            #pragma unroll
            for (int k = 0; k < 4; ++k)
                accS[jt][k] = (f32x4){0.f, 0.f, 0.f, 0.f};

        u32x4 hA[4];                      // A-side H fragments (this wave's rows)
        #pragma unroll
        for (int dt = 0; dt < 4; ++dt)
            hA[dt] = *(const u32x4*)(const void*)(sh + H_OFF + (it * 16 + c) * H_S + dt * 32 + goff);

        #pragma unroll
        for (int pass = 0; pass < 2; ++pass) {
            // build A-frags U = h⊙(0.6 a_k), V = |h|⊙(0.4 a_k) for 2 k's
            u32x4 Uf[4][2], Vf[4][2];
            #pragma unroll
            for (int dt = 0; dt < 4; ++dt) {
                #pragma unroll
                for (int kk = 0; kk < 2; ++kk) {
                    const int k = pass * 2 + kk;
                    const float* ap = (k == 0) ? a0 : (k == 1) ? a1 : (k == 2) ? a2 : a3;
                    const float4 aL = *(const float4*)(ap + dt * 32 + goff);
                    const float4 aH = *(const float4*)(ap + dt * 32 + goff + 4);
                    const float av8[8] = {aL.x, aL.y, aL.z, aL.w, aH.x, aH.y, aH.z, aH.w};
                    u32x4 U, V;
                    #pragma unroll
                    for (int p = 0; p < 4; ++p) {
                        const unsigned int hp = hA[dt][p];
                        const float h0 = bf2f(hp & 0xffffu);
                        const float h1 = bf2f(hp >> 16);
                        const float u0 = 0.6f * av8[2 * p] * h0;
                        const float u1 = 0.6f * av8[2 * p + 1] * h1;
                        const float v0 = 0.4f * av8[2 * p] * fabsf(h0);
                        const float v1 = 0.4f * av8[2 * p + 1] * fabsf(h1);
                        U[p] = (unsigned)f2bf(u0) | ((unsigned)f2bf(u1) << 16);
                        V[p] = (unsigned)f2bf(v0) | ((unsigned)f2bf(v1) << 16);
                    }
                    Uf[dt][kk] = U; Vf[dt][kk] = V;
                }
            }
            #pragma unroll
            for (int jt = 0; jt < 4; ++jt) {
                #pragma unroll
                for (int dt = 0; dt < 4; ++dt) {
                    const u32x4 hB = *(const u32x4*)(const void*)(sh + H_OFF + (jt * 16 + c) * H_S + dt * 32 + goff);
                    u32x4 hBa;
                    #pragma unroll
                    for (int p = 0; p < 4; ++p) hBa[p] = hB[p] & 0x7fff7fffu;
                    #pragma unroll
                    for (int kk = 0; kk < 2; ++kk) {
                        accS[jt][pass * 2 + kk] = mfma16(Uf[dt][kk], hB,  accS[jt][pass * 2 + kk]);
                        accS[jt][pass * 2 + kk] = mfma16(Vf[dt][kk], hBa, accS[jt][pass * 2 + kk]);
                    }
                }
            }
        }

        // ---- adj-select + in-register row softmax (C/D: col=lane&15, row=g*4+reg) ----
        float s_[4][4];                   // [jt][reg]
        #pragma unroll
        for (int jt = 0; jt < 4; ++jt) {
            #pragma unroll
            for (int reg = 0; reg < 4; ++reg) {
                const int i = it * 16 + g * 4 + reg;
                const int j = jt * 16 + c;
                const int ii = (i < NN) ? i : NN - 1;   // clamp: no OOB fault
                const int jj = (j < NN) ? j : NN - 1;
                const int a = adj[((size_t)b * NN + ii) * NN + jj];
                const float c1 = accS[jt][0][reg], c2 = accS[jt][1][reg];
                const float c3 = accS[jt][2][reg], c4 = accS[jt][3][reg];
                float sv = (a == 1) ? c1 : (a == 2) ? c2 : (a == 3) ? c3 : (a == 4) ? c4 : NEGV;
                if (j >= NN) sv = -INFINITY;            // pad col: exp -> 0
                s_[jt][reg] = sv;
            }
        }
        #pragma unroll
        for (int reg = 0; reg < 4; ++reg) {
            float m = fmaxf(fmaxf(s_[0][reg], s_[1][reg]), fmaxf(s_[2][reg], s_[3][reg]));
            m = fmaxf(m, __shfl_xor(m, 1));
            m = fmaxf(m, __shfl_xor(m, 2));
            m = fmaxf(m, __shfl_xor(m, 4));
            m = fmaxf(m, __shfl_xor(m, 8));
            const float p0 = __expf(s_[0][reg] - m);
            const float p1 = __expf(s_[1][reg] - m);
            const float p2 = __expf(s_[2][reg] - m);
            const float p3 = __expf(s_[3][reg] - m);
            float sum = (p0 + p1) + (p2 + p3);
            sum += __shfl_xor(sum, 1);
            sum += __shfl_xor(sum, 2);
            sum += __shfl_xor(sum, 4);
            sum += __shfl_xor(sum, 8);
            const float r = 1.0f / sum;
            const int row = it * 16 + g * 4 + reg;
            sh[AL_OFF + row * AL_S +  0 + c] = f2bf(p0 * r);
            sh[AL_OFF + row * AL_S + 16 + c] = f2bf(p1 * r);
            sh[AL_OFF + row * AL_S + 32 + c] = f2bf(p2 * r);
            sh[AL_OFF + row * AL_S + 48 + c] = f2bf(p3 * r);
        }
        __syncthreads();

        // ---- output = alpha @ H via MFMA (B-frags from HT; pad cols are zero) ----
        const u32x4 pa0 = *(const u32x4*)(const void*)(sh + AL_OFF + (it * 16 + c) * AL_S + goff);
        const u32x4 pa1 = *(const u32x4*)(const void*)(sh + AL_OFF + (it * 16 + c) * AL_S + 32 + goff);
        f32x4 accO[8];
        #pragma unroll
        for (int nt = 0; nt < 8; ++nt) accO[nt] = (f32x4){0.f, 0.f, 0.f, 0.f};
        #pragma unroll
        for (int nt = 0; nt < 8; ++nt) {
            const u32x4 v0 = *(const u32x4*)(const void*)(sh + HT_OFF + (nt * 16 + c) * HT_S + goff);
            const u32x4 v1 = *(const u32x4*)(const void*)(sh + HT_OFF + (nt * 16 + c) * HT_S + 32 + goff);
            accO[nt] = mfma16(pa0, v0, accO[nt]);
            accO[nt] = mfma16(pa1, v1, accO[nt]);
        }
        #pragma unroll
        for (int nt = 0; nt < 8; ++nt) {
            #pragma unroll
            for (int reg = 0; reg < 4; ++reg) {
                const int i = it * 16 + g * 4 + reg;
                if (i < NN)
                    out[((size_t)b * NN + i) * DD + nt * 16 + c] = accO[nt][reg];
            }
        }
    } else {
        // ---------- attr_sess = A_attr @ attr_emb : 2 rows/block, 2-way k-split ----------
        float* red = (float*)sh;            // [2][2][DD] = 512 floats (aliases GAT LDS)
        const int b0 = (blk - BB) * 2;
        const int d  = tid & 127;
        const int kh = tid >> 7;
        const float* Ar0 = A_attr + (size_t)(b0 + 0) * MAXA;
        const float* Ar1 = A_attr + (size_t)(b0 + 1) * MAXA;
        float c0a = 0.f, c0b = 0.f, c1a = 0.f, c1b = 0.f;
        const int k0 = kh * (MAXA / 2);
        for (int k = k0; k < k0 + MAXA / 2; k += 2) {
            const float e0 = attr_emb[(size_t)k * DD + d];
            const float e1 = attr_emb[(size_t)(k + 1) * DD + d];
            c0a = fmaf(Ar0[k], e0, c0a); c0b = fmaf(Ar0[k + 1], e1, c0b);
            c1a = fmaf(Ar1[k], e0, c1a); c1b = fmaf(Ar1[k + 1], e1, c1b);
        }
        red[(kh * 2 + 0) * DD + d] = c0a + c0b;
        red[(kh * 2 + 1) * DD + d] = c1a + c1b;
        __syncthreads();
        if (tid < 2 * DD) {
            const int r  = tid >> 7;
            const int dd = tid & 127;
            attr_out[(size_t)(b0 + r) * DD + dd] =
                red[(0 * 2 + r) * DD + dd] + red[(1 * 2 + r) * DD + dd];
        }
    }
}

extern "C" void kernel_launch(void* const* d_in, const int* in_sizes, int n_in,
                              void* d_out, int out_size, void* d_ws, size_t ws_size,
                              hipStream_t stream) {
    const int*   inputs    = (const int*)  d_in[0];
    const int*   adj       = (const int*)  d_in[1];
    // d_in[2] = mask_item (unused by the reference)
    const float* A_attr    = (const float*)d_in[3];
    const float* embedding = (const float*)d_in[4];
    const float* attr_emb  = (const float*)d_in[5];
    const float* a0        = (const float*)d_in[6];
    const float* a1        = (const float*)d_in[7];
    const float* a2        = (const float*)d_in[8];
    const float* a3        = (const float*)d_in[9];

    float* out      = (float*)d_out;                 // [B,N,D] flat
    float* attr_out = out + (size_t)BB * NN * DD;    // [B,D] flat, concatenated

    const int grid = BB + BB / 2;  // 256 GAT blocks + 128 attr blocks
    sg_fused_kernel<<<grid, 256, 0, stream>>>(inputs, adj, A_attr, embedding,
                                              attr_emb, a0, a1, a2, a3,
                                              out, attr_out);
}

// Round 4
// 52.421 us; speedup vs baseline: 1.3908x; 1.1718x over previous
//
#include <hip/hip_runtime.h>
#include <math.h>

#define BB 256
#define NN 50
#define DD 128
#define MAXA 2000
#define NEGV -9e15f

// LDS layout (u16 units)
#define H_S   136                     // H [64 rows][col u16, XOR ((row&15)<<3)]
#define HT_S  72                      // HT [128 d-rows][64 i-cols, XOR ((d&7)<<3)]
#define AL_S  72                      // alpha [32 local rows][64 j]
#define H_OFF   0
#define HT_OFF  (64 * H_S)            // 8704
#define AL_OFF  (HT_OFF + 128 * HT_S) // 17920
#define ADJ_OFF (AL_OFF + 32 * AL_S)  // 20224: adj u16 [32][64]
#define ND_OFF  (ADJ_OFF + 32 * 64)   // 22272: 64 u32 node ids
#define RED_OFF (ND_OFF + 128)        // 22400: 256 f32 attr partials
#define LDS_US  (RED_OFF + 512)       // 22912 u16 = 45824 B

typedef __attribute__((ext_vector_type(8))) short        s8b;
typedef __attribute__((ext_vector_type(4))) float        f32x4;
typedef __attribute__((ext_vector_type(4))) unsigned int u32x4;

static __device__ __forceinline__ unsigned short f2bf(float x) {
    unsigned int u = __float_as_uint(x);
    u = u + 0x7fffu + ((u >> 16) & 1u);          // RNE
    return (unsigned short)(u >> 16);
}
static __device__ __forceinline__ float bf2f(unsigned int s) {
    return __uint_as_float(s << 16);
}
static __device__ __forceinline__ f32x4 mfma16(u32x4 a, u32x4 b, f32x4 c) {
    return __builtin_amdgcn_mfma_f32_16x16x32_bf16(
        __builtin_bit_cast(s8b, a), __builtin_bit_cast(s8b, b), c, 0, 0, 0);
}

__global__ __launch_bounds__(256) void sg_fused_kernel(
    const int* __restrict__ inputs,      // [B,N]
    const int* __restrict__ adj,         // [B,N,N]
    const float* __restrict__ A_attr,    // [B,MAXA]
    const float* __restrict__ embedding, // [N_NODE,D]
    const float* __restrict__ attr_emb,  // [MAXA,D]
    const float* __restrict__ a0,
    const float* __restrict__ a1,
    const float* __restrict__ a2,
    const float* __restrict__ a3,
    float* __restrict__ out,             // [B,N,D]
    float* __restrict__ attr_out)        // [B,D]
{
    __shared__ __align__(16) unsigned short sh[LDS_US];
    const int blk  = blockIdx.x;
    const int tid  = threadIdx.x;
    const int b    = blk & 255;          // batch
    const int p    = blk >> 8;           // row-half: pair blocks {b, b+256} -> same XCD
    const int R0   = 32 * p;             // this block's first output row
    const int w    = tid >> 6;           // wave 0..3
    const int lane = tid & 63;
    const int g    = lane >> 4;          // k-group
    const int c    = lane & 15;
    const int goff = g * 8;

    unsigned int* ndp  = (unsigned int*)(sh + ND_OFF);
    float*        redp = (float*)(sh + RED_OFF);

    // ---------------- stage 0: node ids + adj rows -> LDS ----------------
    if (tid < 64) ndp[tid] = (tid < NN) ? (unsigned)inputs[b * NN + tid] : 0u;
    #pragma unroll
    for (int n = 0; n < 8; ++n) {
        const int il = n * 4 + w;            // local row 0..31 (wave-uniform)
        const int j  = lane;
        const int gi = R0 + il;
        int a = 0;
        if (gi < NN && j < NN) a = adj[((size_t)b * NN + gi) * NN + j];
        sh[ADJ_OFF + il * 64 + j] = (unsigned short)a;
    }
    __syncthreads();

    // ------- stage 1: embedding gather (i-major, 8 independent float4/lane) -------
    {
        const int  i    = lane;
        const int  node = (int)ndp[i];
        const bool live = (i < NN);
        #pragma unroll
        for (int n = 0; n < 8; ++n) {
            const int d4 = w * 8 + n;        // 0..31
            float4 v = make_float4(0.f, 0.f, 0.f, 0.f);
            if (live) v = *(const float4*)(embedding + (size_t)node * DD + d4 * 4);
            const unsigned short b0 = f2bf(v.x), b1 = f2bf(v.y);
            const unsigned short b2 = f2bf(v.z), b3 = f2bf(v.w);
            // H: 8B write, XOR-swizzled col
            const int colx = (d4 * 4) ^ ((i & 15) << 3);
            *(uint2*)(sh + H_OFF + i * H_S + colx) =
                make_uint2((unsigned)b0 | ((unsigned)b1 << 16),
                           (unsigned)b2 | ((unsigned)b3 << 16));
            // HT: lane-contiguous u16 writes (conflict-free), XOR on i-col
            const int dd = d4 * 4;
            sh[HT_OFF + (dd + 0) * HT_S + (i ^ (((dd + 0) & 7) << 3))] = b0;
            sh[HT_OFF + (dd + 1) * HT_S + (i ^ (((dd + 1) & 7) << 3))] = b1;
            sh[HT_OFF + (dd + 2) * HT_S + (i ^ (((dd + 2) & 7) << 3))] = b2;
            sh[HT_OFF + (dd + 3) * HT_S + (i ^ (((dd + 3) & 7) << 3))] = b3;
        }
    }
    __syncthreads();

    if (w < 2) {
        // ============ score waves: rows R0+16w .. +15, full j via MFMA ============
        const int rbase = R0 + 16 * w;
        u32x4 hA[4];
        #pragma unroll
        for (int dt = 0; dt < 4; ++dt)
            hA[dt] = *(const u32x4*)(const void*)(sh + H_OFF + (rbase + c) * H_S +
                                                  ((dt * 32 + goff) ^ (c << 3)));
        f32x4 accS[4][4];                    // [jt][k]
        #pragma unroll
        for (int jt = 0; jt < 4; ++jt)
            #pragma unroll
            for (int k = 0; k < 4; ++k) accS[jt][k] = (f32x4){0.f, 0.f, 0.f, 0.f};

        #pragma unroll
        for (int pass = 0; pass < 2; ++pass) {
            u32x4 Uf[4][2], Vf[4][2];
            #pragma unroll
            for (int dt = 0; dt < 4; ++dt) {
                #pragma unroll
                for (int kk = 0; kk < 2; ++kk) {
                    const int k = pass * 2 + kk;
                    const float* ap = (k == 0) ? a0 : (k == 1) ? a1 : (k == 2) ? a2 : a3;
                    const float4 aL = *(const float4*)(ap + dt * 32 + goff);
                    const float4 aH = *(const float4*)(ap + dt * 32 + goff + 4);
                    const float av8[8] = {aL.x, aL.y, aL.z, aL.w, aH.x, aH.y, aH.z, aH.w};
                    u32x4 U, V;
                    #pragma unroll
                    for (int q = 0; q < 4; ++q) {
                        const unsigned int hp = hA[dt][q];
                        const float h0 = bf2f(hp & 0xffffu);
                        const float h1 = bf2f(hp >> 16);
                        const float u0 = 0.6f * av8[2 * q] * h0;
                        const float u1 = 0.6f * av8[2 * q + 1] * h1;
                        const float v0 = 0.4f * av8[2 * q] * fabsf(h0);
                        const float v1 = 0.4f * av8[2 * q + 1] * fabsf(h1);
                        U[q] = (unsigned)f2bf(u0) | ((unsigned)f2bf(u1) << 16);
                        V[q] = (unsigned)f2bf(v0) | ((unsigned)f2bf(v1) << 16);
                    }
                    Uf[dt][kk] = U; Vf[dt][kk] = V;
                }
            }
            #pragma unroll
            for (int jt = 0; jt < 4; ++jt) {
                #pragma unroll
                for (int dt = 0; dt < 4; ++dt) {
                    const u32x4 hB = *(const u32x4*)(const void*)(sh + H_OFF + (jt * 16 + c) * H_S +
                                                                  ((dt * 32 + goff) ^ (c << 3)));
                    u32x4 hBa;
                    #pragma unroll
                    for (int q = 0; q < 4; ++q) hBa[q] = hB[q] & 0x7fff7fffu;
                    #pragma unroll
                    for (int kk = 0; kk < 2; ++kk) {
                        accS[jt][pass * 2 + kk] = mfma16(Uf[dt][kk], hB,  accS[jt][pass * 2 + kk]);
                        accS[jt][pass * 2 + kk] = mfma16(Vf[dt][kk], hBa, accS[jt][pass * 2 + kk]);
                    }
                }
            }
        }

        // ---- adj select (from LDS) + in-register softmax ----
        float s_[4][4];
        #pragma unroll
        for (int jt = 0; jt < 4; ++jt) {
            #pragma unroll
            for (int reg = 0; reg < 4; ++reg) {
                const int il = 16 * w + g * 4 + reg;     // local row 0..31
                const int j  = jt * 16 + c;
                const int a  = (int)sh[ADJ_OFF + il * 64 + j];
                const float e1 = accS[jt][0][reg], e2 = accS[jt][1][reg];
                const float e3 = accS[jt][2][reg], e4 = accS[jt][3][reg];
                float sv = (a == 1) ? e1 : (a == 2) ? e2 : (a == 3) ? e3 : (a == 4) ? e4 : NEGV;
                if (j >= NN) sv = -INFINITY;
                s_[jt][reg] = sv;
            }
        }
        #pragma unroll
        for (int reg = 0; reg < 4; ++reg) {
            float m = fmaxf(fmaxf(s_[0][reg], s_[1][reg]), fmaxf(s_[2][reg], s_[3][reg]));
            m = fmaxf(m, __shfl_xor(m, 1));
            m = fmaxf(m, __shfl_xor(m, 2));
            m = fmaxf(m, __shfl_xor(m, 4));
            m = fmaxf(m, __shfl_xor(m, 8));
            const float p0 = __expf(s_[0][reg] - m);
            const float p1 = __expf(s_[1][reg] - m);
            const float p2 = __expf(s_[2][reg] - m);
            const float p3 = __expf(s_[3][reg] - m);
            float sum = (p0 + p1) + (p2 + p3);
            sum += __shfl_xor(sum, 1);
            sum += __shfl_xor(sum, 2);
            sum += __shfl_xor(sum, 4);
            sum += __shfl_xor(sum, 8);
            const float r  = 1.0f / sum;
            const int  il  = 16 * w + g * 4 + reg;
            sh[AL_OFF + il * AL_S +  0 + c] = f2bf(p0 * r);
            sh[AL_OFF + il * AL_S + 16 + c] = f2bf(p1 * r);
            sh[AL_OFF + il * AL_S + 32 + c] = f2bf(p2 * r);
            sh[AL_OFF + il * AL_S + 48 + c] = f2bf(p3 * r);
        }
    } else {
        // ============ attr waves: one full attr row per chosen block ============
        if (p == (b & 1)) {
            const int    kb = (w - 2) * (MAXA / 2);
            const float* Ar = A_attr + (size_t)b * MAXA;
            const int    d0 = lane * 2;
            float ax = 0.f, ay = 0.f, bx = 0.f, by = 0.f;
            #pragma unroll 4
            for (int k = kb; k < kb + MAXA / 2; k += 2) {
                const float2 e0 = *(const float2*)(attr_emb + (size_t)k * DD + d0);
                const float2 e1 = *(const float2*)(attr_emb + (size_t)(k + 1) * DD + d0);
                const float w0 = Ar[k], w1 = Ar[k + 1];
                ax = fmaf(w0, e0.x, ax); ay = fmaf(w0, e0.y, ay);
                bx = fmaf(w1, e1.x, bx); by = fmaf(w1, e1.y, by);
            }
            redp[(w - 2) * 128 + d0]     = ax + bx;
            redp[(w - 2) * 128 + d0 + 1] = ay + by;
        }
    }
    __syncthreads();

    // attr final store (wave 2 of chosen blocks)
    if (w == 2 && p == (b & 1)) {
        const int d0 = lane * 2;
        float2 o;
        o.x = redp[d0]     + redp[128 + d0];
        o.y = redp[d0 + 1] + redp[128 + d0 + 1];
        *(float2*)(attr_out + (size_t)b * DD + d0) = o;
    }

    // ---------------- PV: all 4 waves, 4 tiles each ----------------
    #pragma unroll
    for (int n = 0; n < 4; ++n) {
        const int t   = w + 4 * n;           // 0..15
        const int itl = t >> 3;              // 0..1
        const int nt  = t & 7;               // 0..7
        const int il  = itl * 16 + c;        // alpha local row
        const u32x4 pa0 = *(const u32x4*)(const void*)(sh + AL_OFF + il * AL_S + goff);
        const u32x4 pa1 = *(const u32x4*)(const void*)(sh + AL_OFF + il * AL_S + 32 + goff);
        const int d = nt * 16 + c;           // HT row (output dim)
        const u32x4 v0 = *(const u32x4*)(const void*)(sh + HT_OFF + d * HT_S + ((0  + goff) ^ ((c & 7) << 3)));
        const u32x4 v1 = *(const u32x4*)(const void*)(sh + HT_OFF + d * HT_S + ((32 + goff) ^ ((c & 7) << 3)));
        f32x4 acc = (f32x4){0.f, 0.f, 0.f, 0.f};
        acc = mfma16(pa0, v0, acc);
        acc = mfma16(pa1, v1, acc);
        #pragma unroll
        for (int reg = 0; reg < 4; ++reg) {
            const int ig = R0 + itl * 16 + g * 4 + reg;
            if (ig < NN)
                out[((size_t)b * NN + ig) * DD + nt * 16 + c] = acc[reg];
        }
    }
}

extern "C" void kernel_launch(void* const* d_in, const int* in_sizes, int n_in,
                              void* d_out, int out_size, void* d_ws, size_t ws_size,
                              hipStream_t stream) {
    const int*   inputs    = (const int*)  d_in[0];
    const int*   adj       = (const int*)  d_in[1];
    // d_in[2] = mask_item (unused by the reference)
    const float* A_attr    = (const float*)d_in[3];
    const float* embedding = (const float*)d_in[4];
    const float* attr_emb  = (const float*)d_in[5];
    const float* a0        = (const float*)d_in[6];
    const float* a1        = (const float*)d_in[7];
    const float* a2        = (const float*)d_in[8];
    const float* a3        = (const float*)d_in[9];

    float* out      = (float*)d_out;                 // [B,N,D] flat
    float* attr_out = out + (size_t)BB * NN * DD;    // [B,D] flat, concatenated

    sg_fused_kernel<<<512, 256, 0, stream>>>(inputs, adj, A_attr, embedding,
                                             attr_emb, a0, a1, a2, a3,
                                             out, attr_out);
}